// Round 3
// baseline (988.312 us; speedup 1.0000x reference)
//
#include <hip/hip_runtime.h>

#define NN 50000
#define NE 800000

// ---------------- Fused LayerNorm + QKV GEMM ------------------------------
// One output row per lane; column block of 64 per blockIdx.y.
__global__ __launch_bounds__(256) void ln_qkv(
    const float* __restrict__ x, const float* __restrict__ g,
    const float* __restrict__ b, const float* __restrict__ W,
    const float* __restrict__ bias, float* __restrict__ Out, int M) {
  const int Nw = 384;
  int row  = blockIdx.x * 256 + threadIdx.x;
  int n0   = blockIdx.y * 64;
  bool live = row < M;
  const float* xr = x + (size_t)(live ? row : 0) * 128;

  float sum = 0.f, sq = 0.f;
  for (int k = 0; k < 128; k += 4) {
    float4 a = *(const float4*)(xr + k);
    sum += a.x + a.y + a.z + a.w;
    sq  += a.x * a.x + a.y * a.y + a.z * a.z + a.w * a.w;
  }
  float mu  = sum * (1.f / 128.f);
  float var = sq * (1.f / 128.f) - mu * mu;
  float inv = rsqrtf(var + 1e-5f);

  float acc[64];
#pragma unroll
  for (int j = 0; j < 64; ++j) acc[j] = 0.f;

  for (int k = 0; k < 128; k += 4) {
    float4 a  = *(const float4*)(xr + k);
    float4 gg = *(const float4*)(g + k);   // uniform
    float4 bb = *(const float4*)(b + k);   // uniform
    float an[4];
    an[0] = (a.x - mu) * inv * gg.x + bb.x;
    an[1] = (a.y - mu) * inv * gg.y + bb.y;
    an[2] = (a.z - mu) * inv * gg.z + bb.z;
    an[3] = (a.w - mu) * inv * gg.w + bb.w;
#pragma unroll
    for (int t = 0; t < 4; ++t) {
      float ak = an[t];
      const float* wr = W + (size_t)(k + t) * Nw + n0;  // wave-uniform
#pragma unroll
      for (int j = 0; j < 16; ++j) {
        float4 w = *(const float4*)(wr + 4 * j);
        acc[4 * j + 0] += ak * w.x;
        acc[4 * j + 1] += ak * w.y;
        acc[4 * j + 2] += ak * w.z;
        acc[4 * j + 3] += ak * w.w;
      }
    }
  }

  if (!live) return;
  float* o = Out + (size_t)row * Nw + n0;
#pragma unroll
  for (int j = 0; j < 16; ++j) {
    float4 bb = *(const float4*)(bias + n0 + 4 * j);  // uniform
    float4 ov;
    ov.x = acc[4 * j + 0] + bb.x;
    ov.y = acc[4 * j + 1] + bb.y;
    ov.z = acc[4 * j + 2] + bb.z;
    ov.w = acc[4 * j + 3] + bb.w;
    *(float4*)(o + 4 * j) = ov;
  }
}

// ---------------- K=128 fp32 GEMM, row-per-lane (out-projection) -----------
__global__ __launch_bounds__(256) void gemm_rw(
    const float* __restrict__ A, const float* __restrict__ W,
    const float* __restrict__ bias, const float* __restrict__ resid,
    float* __restrict__ Out, int M, int Nw) {
  int row  = blockIdx.x * 256 + threadIdx.x;
  int n0   = blockIdx.y * 64;
  bool live = row < M;
  const float* Ar = A + (size_t)(live ? row : 0) * 128;

  float acc[64];
#pragma unroll
  for (int j = 0; j < 64; ++j) acc[j] = 0.f;

  for (int k = 0; k < 128; k += 4) {
    float4 a4 = *(const float4*)(Ar + k);
#pragma unroll
    for (int t = 0; t < 4; ++t) {
      float ak = (t == 0) ? a4.x : (t == 1) ? a4.y : (t == 2) ? a4.z : a4.w;
      const float* wr = W + (size_t)(k + t) * Nw + n0;  // wave-uniform
#pragma unroll
      for (int j = 0; j < 16; ++j) {
        float4 w = *(const float4*)(wr + 4 * j);
        acc[4 * j + 0] += ak * w.x;
        acc[4 * j + 1] += ak * w.y;
        acc[4 * j + 2] += ak * w.z;
        acc[4 * j + 3] += ak * w.w;
      }
    }
  }

  if (!live) return;
  float* o = Out + (size_t)row * Nw + n0;
  const float* r = resid + (size_t)row * Nw + n0;
#pragma unroll
  for (int j = 0; j < 16; ++j) {
    float4 bb = *(const float4*)(bias + n0 + 4 * j);  // uniform
    float4 rv = *(const float4*)(r + 4 * j);
    float4 ov;
    ov.x = acc[4 * j + 0] + bb.x + rv.x;
    ov.y = acc[4 * j + 1] + bb.y + rv.y;
    ov.z = acc[4 * j + 2] + bb.z + rv.z;
    ov.w = acc[4 * j + 3] + bb.w + rv.w;
    *(float4*)(o + 4 * j) = ov;
  }
}

// ---------------- CSR build ----------------
__global__ __launch_bounds__(256) void count_kernel(
    const int* __restrict__ ei, int* __restrict__ cnt, int E) {
  int e = blockIdx.x * blockDim.x + threadIdx.x;
  if (e >= E) return;
  atomicAdd(&cnt[ei[E + e]], 1);  // dst row
}

__global__ __launch_bounds__(256) void block_sums(
    const int* __restrict__ cnt, int* __restrict__ bsum, int n) {
  int i = blockIdx.x * 256 + threadIdx.x;
  int v = (i < n) ? cnt[i] : 0;
#pragma unroll
  for (int o = 32; o > 0; o >>= 1) v += __shfl_down(v, o);
  __shared__ int ws[4];
  if ((threadIdx.x & 63) == 0) ws[threadIdx.x >> 6] = v;
  __syncthreads();
  if (threadIdx.x == 0) bsum[blockIdx.x] = ws[0] + ws[1] + ws[2] + ws[3];
}

__global__ __launch_bounds__(256) void scan_write(
    const int* __restrict__ cnt, const int* __restrict__ bsum,
    int* __restrict__ row_start, int* __restrict__ cursor, int n, int total) {
  __shared__ int wred[4];
  __shared__ int wsum[4];
  __shared__ int off_s;
  int b = blockIdx.x, tid = threadIdx.x;

  int v = (tid < b) ? bsum[tid] : 0;
#pragma unroll
  for (int o = 32; o > 0; o >>= 1) v += __shfl_down(v, o);
  if ((tid & 63) == 0) wred[tid >> 6] = v;
  __syncthreads();
  if (tid == 0) off_s = wred[0] + wred[1] + wred[2] + wred[3];

  int i = b * 256 + tid;
  int c = (i < n) ? cnt[i] : 0;
  int xv = c;
#pragma unroll
  for (int o = 1; o < 64; o <<= 1) {
    int t = __shfl_up(xv, o);
    if ((tid & 63) >= o) xv += t;
  }
  if ((tid & 63) == 63) wsum[tid >> 6] = xv;
  __syncthreads();

  int w = tid >> 6;
  int woff = off_s;
  if (w > 0) woff += wsum[0];
  if (w > 1) woff += wsum[1];
  if (w > 2) woff += wsum[2];
  int excl = woff + xv - c;
  if (i < n) {
    row_start[i] = excl;
    cursor[i]    = excl;
  }
  if (i == 0) row_start[n] = total;
}

// scatter sorted-by-dst adjacency: adj[pos] = {src, edge_id}
__global__ __launch_bounds__(256) void scatter_kernel(
    const int* __restrict__ ei, int* __restrict__ cursor,
    int2* __restrict__ adj, int E) {
  int e = blockIdx.x * blockDim.x + threadIdx.x;
  if (e >= E) return;
  int pos = atomicAdd(&cursor[ei[E + e]], 1);
  adj[pos] = make_int2(ei[e], e);
}

// ---------------- Fused per-node attention, edge-parallel scores -----------
// One wave per node. lane = h*8 + t (head h, edge-slot t).
// Each step handles 8 edges: lane computes the FULL 16-dim score dot for
// (edge t, head h). One group-max + one exp per 8 edges (vs per-edge before).
// Defer-rescale (threshold 8, wave-uniform __all) keeps the serial chain short.
// V aggregation: row base via __shfl(sL, j) with literal j -> v_readlane
// (scalar base); only pe broadcast needs bpermute.
__global__ __launch_bounds__(256) void fused_attn(
    const float* __restrict__ qkv, const float* __restrict__ edge_attr,
    const int2* __restrict__ adj, const int* __restrict__ row_start,
    float* __restrict__ agg, int N) {
  int node = (blockIdx.x * blockDim.x + threadIdx.x) >> 6;
  if (node >= N) return;
  int lane = threadIdx.x & 63;
  int h = lane >> 3, t = lane & 7;
  int ch = lane * 2;  // == h*16 + t*2

  const float* qb = qkv + (size_t)node * 384 + h * 16;
  float4 q0 = *(const float4*)(qb + 0);
  float4 q1 = *(const float4*)(qb + 4);
  float4 q2 = *(const float4*)(qb + 8);
  float4 q3 = *(const float4*)(qb + 12);

  float m = -INFINITY, l = 0.f;
  float2 acc = make_float2(0.f, 0.f);

  int beg  = row_start[node];
  int stop = row_start[node + 1];

  for (int c0 = beg; c0 < stop; c0 += 64) {
    int nc = min(64, stop - c0);
    int sl = 0, el = 0;
    if (lane < nc) {
      int2 ae = adj[c0 + lane];  // coalesced 8B
      sl = ae.x;
      el = ae.y;
    }
    for (int j0 = 0; j0 < nc; j0 += 8) {
      int idx = j0 + t;                  // this lane's edge slot
      int sL = __shfl(sl, idx);
      int eL = __shfl(el, idx);
      const float* kb = qkv + (size_t)sL * 384 + 128 + h * 16;
      const float* ab = edge_attr + (size_t)eL * 128 + h * 16;
      float4 k0 = *(const float4*)(kb + 0);
      float4 k1 = *(const float4*)(kb + 4);
      float4 k2 = *(const float4*)(kb + 8);
      float4 k3 = *(const float4*)(kb + 12);
      float4 a0 = *(const float4*)(ab + 0);
      float4 a1 = *(const float4*)(ab + 4);
      float4 a2 = *(const float4*)(ab + 8);
      float4 a3 = *(const float4*)(ab + 12);
      float d;
      d  = q0.x * (k0.x + a0.x) + q0.y * (k0.y + a0.y) +
           q0.z * (k0.z + a0.z) + q0.w * (k0.w + a0.w);
      d += q1.x * (k1.x + a1.x) + q1.y * (k1.y + a1.y) +
           q1.z * (k1.z + a1.z) + q1.w * (k1.w + a1.w);
      d += q2.x * (k2.x + a2.x) + q2.y * (k2.y + a2.y) +
           q2.z * (k2.z + a2.z) + q2.w * (k2.w + a2.w);
      d += q3.x * (k3.x + a3.x) + q3.y * (k3.y + a3.y) +
           q3.z * (k3.z + a3.z) + q3.w * (k3.w + a3.w);
      float s = (idx < nc) ? d * 0.25f : -INFINITY;

      float mx = s;
      mx = fmaxf(mx, __shfl_xor(mx, 1));
      mx = fmaxf(mx, __shfl_xor(mx, 2));
      mx = fmaxf(mx, __shfl_xor(mx, 4));  // max over the 8 slots of head h

      if (!__all(mx <= m + 8.f)) {        // wave-uniform rescale (rare)
        float mn = fmaxf(m, mx);
        float sc = __expf(m - mn);        // m=-inf first step -> 0, no NaN
        l *= sc;
        acc.x *= sc;
        acc.y *= sc;
        m = mn;
      }
      float pe = __expf(s - m);           // one exp covers all 8 edges x heads

      float ls = pe;
      ls += __shfl_xor(ls, 1);
      ls += __shfl_xor(ls, 2);
      ls += __shfl_xor(ls, 4);
      l += ls;

      int gbase = lane & 56;
#pragma unroll
      for (int j = 0; j < 8; ++j) {
        int sj = __shfl(sL, j);           // literal lane -> v_readlane (scalar)
        float pj = __shfl(pe, gbase + j); // per-head broadcast (bpermute)
        float2 vv = *(const float2*)(qkv + (size_t)sj * 384 + 256 + ch);
        acc.x += pj * vv.x;
        acc.y += pj * vv.y;
      }
    }
  }
  float inv = 1.f / fmaxf(l, 1e-16f);
  float2 o = make_float2(acc.x * inv, acc.y * inv);
  *(float2*)(agg + (size_t)node * 128 + ch) = o;
}

extern "C" void kernel_launch(void* const* d_in, const int* in_sizes, int n_in,
                              void* d_out, int out_size, void* d_ws,
                              size_t ws_size, hipStream_t stream) {
  const float* x         = (const float*)d_in[0];
  const float* edge_attr = (const float*)d_in[1];
  const float* qkv_w     = (const float*)d_in[2];
  const float* qkv_b     = (const float*)d_in[3];
  const float* out_w     = (const float*)d_in[4];
  const float* out_b     = (const float*)d_in[5];
  const float* ln_g      = (const float*)d_in[6];
  const float* ln_b      = (const float*)d_in[7];
  const int*   ei        = (const int*)d_in[8];
  float* out = (float*)d_out;

  const int N = NN, E = NE;
  const int NB = (N + 255) / 256;  // 196
  float* qkv       = (float*)d_ws;                        // N*384 f
  float* agg       = qkv + (size_t)N * 384;               // N*128 f
  int*   cnt       = (int*)(agg + (size_t)N * 128);       // N
  int*   bsum      = cnt + N;                             // 256
  int*   row_start = bsum + 256;                          // N+1
  int*   cursor    = row_start + N + 1;                   // N
  int2*  adj       = (int2*)(cursor + N);                 // E int2

  // --- CSR build ---
  hipMemsetAsync(cnt, 0, (size_t)N * 4, stream);
  count_kernel<<<(E + 255) / 256, 256, 0, stream>>>(ei, cnt, E);
  block_sums<<<NB, 256, 0, stream>>>(cnt, bsum, N);
  scan_write<<<NB, 256, 0, stream>>>(cnt, bsum, row_start, cursor, N, E);
  scatter_kernel<<<(E + 255) / 256, 256, 0, stream>>>(ei, cursor, adj, E);

  // --- 1. LayerNorm + QKV projection (fused) ---
  dim3 g1(NB, 384 / 64);
  ln_qkv<<<g1, 256, 0, stream>>>(x, ln_g, ln_b, qkv_w, qkv_b, qkv, N);

  // --- 2. fused attention (scores + softmax + aggregate) ---
  fused_attn<<<(N * 64 + 255) / 256, 256, 0, stream>>>(
      qkv, edge_attr, adj, row_start, agg, N);

  // --- 3. output projection + bias + residual ---
  dim3 g2(NB, 128 / 64);
  gemm_rw<<<g2, 256, 0, stream>>>(agg, out_w, out_b, x, out, N, 128);
}